// Round 7
// baseline (299.766 us; speedup 1.0000x reference)
//
#include <hip/hip_runtime.h>
#include <hip/hip_bf16.h>

#define K_DIM 4096
#define N_DIM 4096
#define M_DIM 4096

typedef __attribute__((ext_vector_type(8)))  short bf16x8;    // 8 bf16, 4 VGPRs
typedef __attribute__((ext_vector_type(4)))  float f32x4;     // 16x16 MFMA acc
typedef __attribute__((ext_vector_type(16))) float f32x16;    // 32x32 MFMA acc (fallback)
typedef __attribute__((ext_vector_type(8)))  unsigned short u16x8;

// ---------- fp32 -> bf16 (round-to-nearest-even) ----------
__device__ __forceinline__ unsigned short f2bf(float f) {
    union { float f; unsigned int u; } v; v.f = f;
    unsigned int u = v.u;
    return (unsigned short)((u + 0x7fffu + ((u >> 16) & 1u)) >> 16);
}

// ---------- fused convert: x and W in one launch ----------
__global__ void cvt2_f32_to_bf16(const float* __restrict__ x,
                                 const float* __restrict__ W,
                                 unsigned short* __restrict__ xb,
                                 unsigned short* __restrict__ wb,
                                 int blocks_each) {
    int b = blockIdx.x;
    const float* src = x;
    unsigned short* dst = xb;
    if (b >= blocks_each) { b -= blocks_each; src = W; dst = wb; }
    const int i = (b * 256 + threadIdx.x) * 8;
    float4 f0 = *(const float4*)(src + i);
    float4 f1 = *(const float4*)(src + i + 4);
    u16x8 o;
    o[0] = f2bf(f0.x); o[1] = f2bf(f0.y); o[2] = f2bf(f0.z); o[3] = f2bf(f0.w);
    o[4] = f2bf(f1.x); o[5] = f2bf(f1.y); o[6] = f2bf(f1.z); o[7] = f2bf(f1.w);
    *(u16x8*)(dst + i) = o;
}

// ---------- async global->LDS, 16B per lane (dest = wave-uniform base + lane*16) ----------
__device__ __forceinline__ void gl_lds16(const void* g, void* l) {
    __builtin_amdgcn_global_load_lds(
        (const __attribute__((address_space(1))) void*)g,
        (__attribute__((address_space(3))) void*)l,
        16, 0, 0);
}

// ============================================================================
// V7: TWO independent blocks per CU (the overlap the single-block structure
// never achieved intra-block).  256x128 tile, BK=32, 256 threads (4 waves,
// 2M x 2N, per-wave 128x64 output - identical wave tile to V1-V3).
//   LDS/block = 48 KiB: [buf(2) x (A 256x32 | B 128x32)] shorts, granule
//   slot q holds global granule q ^ ((row>>1)&3) (0-conflict pattern,
//   measured R1/R2).  LDS fits 3 blocks, VGPR fits 2 -> exactly 2/CU:
//   block A's MFMA window overlaps block B's LDS drain via the CU scheduler
//   (independent barriers), instead of 8 barrier-locked waves alternating.
// Per K-tile (2 barriers only):
//   {12 ds_read_b128; 32 MFMA (compiler interleaves, auto-lgkm);
//    BAR  (reads all consumed: MFMA issues in-order after operand reads);
//    stage tile t+2 into SAME buf (6 gl_lds); vmcnt(6) = t+1 landed,
//    t+2 stays in flight (never 0 mid-loop); BAR (t+1 globally visible)}
// ============================================================================
__global__ __launch_bounds__(256, 2) void gemm256(
    const unsigned short* __restrict__ A,   // [M,K] bf16
    const unsigned short* __restrict__ B,   // [N,K] bf16
    const float* __restrict__ bias, float* __restrict__ C) {

    __shared__ __align__(16) unsigned short sh[24576];   // 48 KiB

    const int tid  = threadIdx.x;
    const int wave = tid >> 6;
    const int lane = tid & 63;
    const int l16  = lane & 15;
    const int gq   = lane >> 4;        // k-granule 0..3
    const int wm   = wave >> 1;        // 0..1  (M half: 128 rows)
    const int wn   = wave & 1;         // 0..1  (N half: 64 cols)

    // XCD swizzle: 512 blocks over 8 XCDs; per-XCD 4mt x 16nt patch.
    const int bid = blockIdx.x;
    const int xcd = bid & 7;
    const int idx = bid >> 3;                          // 0..63
    const int mt  = ((xcd >> 1) << 2) + (idx >> 4);    // 0..15 (256-row tiles)
    const int nt  = ((xcd & 1) << 4) + (idx & 15);     // 0..31 (128-col tiles)
    const size_t bm = (size_t)mt << 8;
    const size_t bn = (size_t)nt << 7;

    // ---- staging geometry: granule g = L*256 + tid; row = L*64 + (tid>>2),
    // linear slot tid&3, source slot = slot ^ ((row>>1)&3) = ^((tid>>3)&3).
    const int srow  = tid >> 2;                              // 0..63
    const int sq8   = ((tid & 3) ^ ((tid >> 3) & 3)) << 3;   // inverse-swizzled src granule
    const int wslot = wave << 9;                             // wave*512 shorts (64 granules)

    const unsigned short* Abase = A + bm * K_DIM;
    const unsigned short* Bbase = B + bn * K_DIM;

    auto stageA = [&](int buf, int k0) {
#pragma unroll
        for (int L = 0; L < 4; L++)                          // rows L*64 + srow (0..255)
            gl_lds16(Abase + (size_t)(L * 64 + srow) * K_DIM + k0 + sq8,
                     &sh[buf + L * 2048 + wslot]);
    };
    auto stageB = [&](int buf, int k0) {
#pragma unroll
        for (int L = 0; L < 2; L++)                          // rows L*64 + srow (0..127)
            gl_lds16(Bbase + (size_t)(L * 64 + srow) * K_DIM + k0 + sq8,
                     &sh[buf + 8192 + L * 2048 + wslot]);
    };

    // ---- read-side: frag row = base16 + l16 -> swizzle term = (l16>>1)&3,
    // frag-invariant.  Same 0-conflict pattern as V1-V3 (measured).
    const int koff = (gq ^ ((l16 >> 1) & 3)) << 3;           // shorts
    const int aoff = ((wm << 7) + l16) * 32 + koff;          // A: rows wm*128 + f*16 + l16
    const int boff = ((wn << 6) + l16) * 32 + koff;          // B: rows wn*64  + n*16 + l16

    f32x4 acc[8][4] = {};   // 8 m-frags x 4 n-frags (128 acc regs)
    bf16x8 a[4], b[4];

#define RD_A(base, fbase)                                                     \
    _Pragma("unroll")                                                         \
    for (int f = 0; f < 4; f++)                                               \
        a[f] = *(const bf16x8*)&sh[(base) + aoff + ((fbase) + f) * 512];
#define RD_B(base)                                                            \
    _Pragma("unroll")                                                         \
    for (int n = 0; n < 4; n++)                                               \
        b[n] = *(const bf16x8*)&sh[(base) + boff + n * 512];

#define PHASE_MFMA(FOFF)                                                      \
    __builtin_amdgcn_s_setprio(1);                                            \
    _Pragma("unroll")                                                         \
    for (int f = 0; f < 4; f++)                                               \
        _Pragma("unroll")                                                     \
        for (int n = 0; n < 4; n++)                                           \
            acc[f + FOFF][n] = __builtin_amdgcn_mfma_f32_16x16x32_bf16(       \
                a[f], b[n], acc[f + FOFF][n], 0, 0, 0);                       \
    __builtin_amdgcn_s_setprio(0);

    // ---- prologue: tile0 -> buf0, tile1 -> buf1; vmcnt(6) = tile0's 6 landed
    stageA(0, 0);      stageB(0, 0);
    stageA(12288, 32); stageB(12288, 32);
    asm volatile("s_waitcnt vmcnt(6)" ::: "memory");
    __builtin_amdgcn_s_barrier();

    // stmode: 0 = steady (stage t+2), 1 = t126 (no stage, drain), 2 = t127
    auto ktile = [&](const int buf, const int t, const int stmode) {
        const int A0 = buf, B0 = buf + 8192;

        RD_A(A0, 0)
        RD_B(B0)
        PHASE_MFMA(0)           // compiler interleaves RD_A(4) below with these
        RD_A(A0, 4)
        PHASE_MFMA(4)

        if (stmode == 2) return;                    // straight to epilogue

        // All 12 reads were consumed by in-order MFMA issue above -> this
        // wave's reads of buf are complete; barrier makes it collective.
        __builtin_amdgcn_s_barrier();

        if (stmode == 0) {                          // overwrite buf with t+2
            const int k2 = (t + 2) * 32;
            stageA(buf, k2);
            stageB(buf, k2);
            asm volatile("s_waitcnt vmcnt(6)" ::: "memory");  // t+1 landed
        } else {
            asm volatile("s_waitcnt vmcnt(0)" ::: "memory");  // drain t127
        }
        __builtin_amdgcn_s_barrier();               // t+1 globally visible
    };

    for (int t = 0; t < 126; t += 2) {
        ktile(0,     t,     0);
        ktile(12288, t + 1, 0);
    }
    ktile(0,     126, 1);
    ktile(12288, 127, 2);
#undef PHASE_MFMA
#undef RD_A
#undef RD_B

    // ---- epilogue: 16x16 C/D layout: col = lane&15, row = (lane>>4)*4 + reg
    const size_t row0 = bm + (wm << 7) + (gq << 2);
    const size_t col0 = bn + (wn << 6) + l16;
#pragma unroll
    for (int n = 0; n < 4; n++) {
        const size_t col = col0 + n * 16;
        const float bv = bias[col];
#pragma unroll
        for (int f = 0; f < 8; f++) {
            const size_t r = row0 + f * 16;
#pragma unroll
            for (int j = 0; j < 4; j++)
                C[(r + j) * N_DIM + col] = acc[f][n][j] + bv;
        }
    }
}

// ============================================================================
// Fallback (no workspace): previous-session 128x128 fp32-input kernel, verbatim.
// ============================================================================
#define BM 128
#define BN 128
#define BK 32

__global__ __launch_bounds__(256) void gemm_bt_f32(
    const float* __restrict__ Aptr, const float* __restrict__ Bptr,
    const float* __restrict__ bias, float* __restrict__ C) {

    __shared__ __align__(16) unsigned short As[BM * BK];
    __shared__ __align__(16) unsigned short Bs[BN * BK];

    const int tid  = threadIdx.x;
    const int wave = tid >> 6;
    const int lane = tid & 63;
    const int r32  = lane & 31;
    const int hi   = lane >> 5;

    const int bid = blockIdx.x;
    const int xcd = bid & 7;
    const int idx = bid >> 3;
    const int mt  = ((xcd & 1) << 4) + (idx & 15);
    const int nt  = (((xcd >> 1) & 3) << 3) + (idx >> 4);
    const int bm  = mt * BM;
    const int bn  = nt * BN;

    const int wm = (wave & 1) * 64;
    const int wn = (wave >> 1) * 64;

    f32x16 acc[2][2] = {};
    const int sw = (r32 >> 1) & 3;

    for (int k0 = 0; k0 < K_DIM; k0 += BK) {
        __syncthreads();
        {
            const int r  = tid >> 1;
            const int q0 = (tid & 1) << 1;
            const int s  = (r >> 1) & 3;
            {
                const float* sp = &Aptr[(size_t)(bm + r) * K_DIM + k0 + (q0 << 3)];
                float4 f0 = *(const float4*)(sp + 0);
                float4 f1 = *(const float4*)(sp + 4);
                float4 f2 = *(const float4*)(sp + 8);
                float4 f3 = *(const float4*)(sp + 12);
                u16x8 o0, o1;
                o0[0]=f2bf(f0.x); o0[1]=f2bf(f0.y); o0[2]=f2bf(f0.z); o0[3]=f2bf(f0.w);
                o0[4]=f2bf(f1.x); o0[5]=f2bf(f1.y); o0[6]=f2bf(f1.z); o0[7]=f2bf(f1.w);
                o1[0]=f2bf(f2.x); o1[1]=f2bf(f2.y); o1[2]=f2bf(f2.z); o1[3]=f2bf(f2.w);
                o1[4]=f2bf(f3.x); o1[5]=f2bf(f3.y); o1[6]=f2bf(f3.z); o1[7]=f2bf(f3.w);
                *(u16x8*)&As[r * BK + ((q0 ^ s) << 3)]       = o0;
                *(u16x8*)&As[r * BK + (((q0 + 1) ^ s) << 3)] = o1;
            }
            {
                const float* sp = &Bptr[(size_t)(bn + r) * K_DIM + k0 + (q0 << 3)];
                float4 f0 = *(const float4*)(sp + 0);
                float4 f1 = *(const float4*)(sp + 4);
                float4 f2 = *(const float4*)(sp + 8);
                float4 f3 = *(const float4*)(sp + 12);
                u16x8 o0, o1;
                o0[0]=f2bf(f0.x); o0[1]=f2bf(f0.y); o0[2]=f2bf(f0.z); o0[3]=f2bf(f0.w);
                o0[4]=f2bf(f1.x); o0[5]=f2bf(f1.y); o0[6]=f2bf(f1.z); o0[7]=f2bf(f1.w);
                o1[0]=f2bf(f2.x); o1[1]=f2bf(f2.y); o1[2]=f2bf(f2.z); o1[3]=f2bf(f2.w);
                o1[4]=f2bf(f3.x); o1[5]=f2bf(f3.y); o1[6]=f2bf(f3.z); o1[7]=f2bf(f3.w);
                *(u16x8*)&Bs[r * BK + ((q0 ^ s) << 3)]       = o0;
                *(u16x8*)&Bs[r * BK + (((q0 + 1) ^ s) << 3)] = o1;
            }
        }
        __syncthreads();

        bf16x8 af[2][2], bfv[2][2];
#pragma unroll
        for (int t = 0; t < 2; t++)
#pragma unroll
            for (int h = 0; h < 2; h++) {
                const int koffl = (((hi + 2 * h) ^ sw)) << 3;
                af[t][h]  = *(const bf16x8*)&As[(wm + t * 32 + r32) * BK + koffl];
                bfv[t][h] = *(const bf16x8*)&Bs[(wn + t * 32 + r32) * BK + koffl];
            }
#pragma unroll
        for (int h = 0; h < 2; h++)
#pragma unroll
            for (int i = 0; i < 2; i++)
#pragma unroll
                for (int j = 0; j < 2; j++)
                    acc[i][j] = __builtin_amdgcn_mfma_f32_32x32x16_bf16(
                        af[i][h], bfv[j][h], acc[i][j], 0, 0, 0);
    }

#pragma unroll
    for (int i = 0; i < 2; i++) {
        const int rowb = bm + wm + i * 32 + 4 * hi;
#pragma unroll
        for (int j = 0; j < 2; j++) {
            const int col = bn + wn + j * 32 + r32;
            const float bv = bias[col];
#pragma unroll
            for (int reg = 0; reg < 16; reg++) {
                const int row = rowb + (reg & 3) + 8 * (reg >> 2);
                C[(size_t)row * N_DIM + col] = acc[i][j][reg] + bv;
            }
        }
    }
}

extern "C" void kernel_launch(void* const* d_in, const int* in_sizes, int n_in,
                              void* d_out, int out_size, void* d_ws, size_t ws_size,
                              hipStream_t stream) {
    const float* x = (const float*)d_in[0];   // [M, K]
    const float* W = (const float*)d_in[1];   // [N, K]
    const float* b = (const float*)d_in[2];   // [N]
    float* out = (float*)d_out;               // [M, N]

    const size_t elems = (size_t)M_DIM * K_DIM;
    const size_t need  = 2 * elems * sizeof(unsigned short);  // 64 MB

    if (ws_size >= need) {
        unsigned short* xb = (unsigned short*)d_ws;
        unsigned short* wb = xb + elems;
        const int blocks_each = (int)(elems / (256 * 8));     // 8192
        cvt2_f32_to_bf16<<<2 * blocks_each, 256, 0, stream>>>(x, W, xb, wb, blocks_each);
        dim3 grid((M_DIM / 256) * (N_DIM / 128));             // 512 blocks = 2/CU
        gemm256<<<grid, dim3(256), 0, stream>>>(xb, wb, b, out);
    } else {
        dim3 grid((M_DIM / BM) * (N_DIM / BN));
        gemm_bt_f32<<<grid, dim3(256), 0, stream>>>(x, W, b, out);
    }
}

// Round 8
// 290.219 us; speedup vs baseline: 1.0329x; 1.0329x over previous
//
#include <hip/hip_runtime.h>
#include <hip/hip_bf16.h>

#define K_DIM 4096
#define N_DIM 4096
#define M_DIM 4096

typedef __attribute__((ext_vector_type(8)))  short bf16x8;    // 8 bf16, 4 VGPRs
typedef __attribute__((ext_vector_type(4)))  float f32x4;     // 16x16 MFMA acc
typedef __attribute__((ext_vector_type(16))) float f32x16;    // 32x32 MFMA acc (fallback)
typedef __attribute__((ext_vector_type(8)))  unsigned short u16x8;

// ---------- fp32 -> bf16 (round-to-nearest-even) ----------
__device__ __forceinline__ unsigned short f2bf(float f) {
    union { float f; unsigned int u; } v; v.f = f;
    unsigned int u = v.u;
    return (unsigned short)((u + 0x7fffu + ((u >> 16) & 1u)) >> 16);
}

// ---------- fused convert: x and W in one launch ----------
__global__ void cvt2_f32_to_bf16(const float* __restrict__ x,
                                 const float* __restrict__ W,
                                 unsigned short* __restrict__ xb,
                                 unsigned short* __restrict__ wb,
                                 int blocks_each) {
    int b = blockIdx.x;
    const float* src = x;
    unsigned short* dst = xb;
    if (b >= blocks_each) { b -= blocks_each; src = W; dst = wb; }
    const int i = (b * 256 + threadIdx.x) * 8;
    float4 f0 = *(const float4*)(src + i);
    float4 f1 = *(const float4*)(src + i + 4);
    u16x8 o;
    o[0] = f2bf(f0.x); o[1] = f2bf(f0.y); o[2] = f2bf(f0.z); o[3] = f2bf(f0.w);
    o[4] = f2bf(f1.x); o[5] = f2bf(f1.y); o[6] = f2bf(f1.z); o[7] = f2bf(f1.w);
    *(u16x8*)(dst + i) = o;
}

// ---------- async global->LDS, 16B per lane (dest = wave-uniform base + lane*16) ----------
__device__ __forceinline__ void gl_lds16(const void* g, void* l) {
    __builtin_amdgcn_global_load_lds(
        (const __attribute__((address_space(1))) void*)g,
        (__attribute__((address_space(3))) void*)l,
        16, 0, 0);
}

// ============================================================================
// V8: OCCUPANCY experiment.  Same 256x256 tile / BK=64 / 128KiB LDS / 2-barrier
// K-tile / counted vmcnt as the verified V1-V3 lineage, but 1024 threads =
// 16 waves (4 waves/SIMD, 2x the TLP of every prior round).  Per-wave output
// 64x64 (acc[4][4] f32x4 = 64 regs -> AGPRs).  LDS read traffic/K-tile:
// 16 waves x 16 ds_read_b128 = 262KB (+33% vs 8-wave, still ~= MFMA floor).
// Inner loop is n-major (b[4] live + a[2] rotating) to fit the 128-reg/wave
// combined cap that 16 waves/CU requires; one sched_barrier(0) between
// k-halves stops renaming-hoist from inflating liveness.
// Per K-tile: {16 ds_read_b128 + 32 MFMA (in-order consumption => reads
// retired before last MFMA); BAR; stage t+2 into SAME buf (4 gl_lds, one per
// region); vmcnt(4) = t+1 landed, t+2 in flight (never 0 mid-loop); BAR}.
// LDS layout/swizzle identical to V1-V3 (granule slot q holds global granule
// q ^ ((row>>1)&3); measured 0 bank conflicts).
// ============================================================================
__global__ __launch_bounds__(1024, 1) void gemm256(
    const unsigned short* __restrict__ A,   // [M,K] bf16
    const unsigned short* __restrict__ B,   // [N,K] bf16
    const float* __restrict__ bias, float* __restrict__ C) {

    __shared__ __align__(16) unsigned short sh[65536];   // 128 KiB

    const int tid  = threadIdx.x;
    const int wave = tid >> 6;         // 0..15
    const int lane = tid & 63;
    const int l16  = lane & 15;
    const int gq   = lane >> 4;        // k-granule 0..3
    const int wmr  = (wave >> 2) << 6; // 0,64,128,192  (M block of wave)
    const int wnc  = (wave & 3) << 6;  // 0,64,128,192  (N block of wave)

    // XCD swizzle: 256 blocks over 8 XCDs; per-XCD 4x8 patch of 256^2 tiles.
    const int bid = blockIdx.x;
    const int xcd = bid & 7;
    const int idx = bid >> 3;                          // 0..31
    const int mt  = ((xcd >> 1) << 2) + (idx >> 3);    // 0..15
    const int nt  = ((xcd & 1) << 3) + (idx & 7);      // 0..15
    const size_t bm = (size_t)mt << 8;
    const size_t bn = (size_t)nt << 8;

    // ---- staging: 1024 thr x 16B = 16KB = one region per gl_lds.
    // granule g = tid: row g>>2 (0..255), linear slot g&3, source slot
    // inverse-swizzled: (g&3) ^ ((row>>1)&3) = (g&3) ^ ((g>>3)&3).
    const int srow  = tid >> 2;                              // 0..255
    const int sq8   = ((tid & 3) ^ ((tid >> 3) & 3)) << 3;   // shorts
    const int wslot = wave << 9;                             // wave*512 shorts

    const unsigned short* Abase = A + bm * K_DIM;
    const unsigned short* Bbase = B + bn * K_DIM;

    auto stage = [&](const unsigned short* __restrict__ P, int dstbase, int kelem) {
        gl_lds16(P + (size_t)srow * K_DIM + kelem + sq8, &sh[dstbase + wslot]);
    };

    // ---- read-side: frag row = base64 + f*16 + l16; swizzle term (l16>>1)&3
    // is frag-invariant; 16-lane groups cover all 32 banks 2x -> conflict-free
    // (same pattern as V1-V3, measured 0).
    const int koff = (gq ^ ((l16 >> 1) & 3)) << 3;           // shorts
    const int aoff = (wmr + l16) * 32 + koff;
    const int boff = (wnc + l16) * 32 + koff;

    f32x4 acc[4][4] = {};   // 4 m-frags x 4 n-frags (64 regs -> AGPRs)
    bf16x8 a2[2], b[4];

#define RD_B4(R)                                                              \
    _Pragma("unroll")                                                         \
    for (int n = 0; n < 4; n++)                                               \
        b[n] = *(const bf16x8*)&sh[(R) + boff + n * 512];
#define RD_A2(R, fb)                                                          \
    _Pragma("unroll")                                                         \
    for (int f = 0; f < 2; f++)                                               \
        a2[f] = *(const bf16x8*)&sh[(R) + aoff + ((fb) + f) * 512];
#define MM2(FB)                                                               \
    __builtin_amdgcn_s_setprio(1);                                            \
    _Pragma("unroll")                                                         \
    for (int f = 0; f < 2; f++)                                               \
        _Pragma("unroll")                                                     \
        for (int n = 0; n < 4; n++)                                           \
            acc[(FB) + f][n] = __builtin_amdgcn_mfma_f32_16x16x32_bf16(       \
                a2[f], b[n], acc[(FB) + f][n], 0, 0, 0);                      \
    __builtin_amdgcn_s_setprio(0);

    // ---- prologue: tile0 -> buf0, tile1 -> buf1 (4 loads each); vmcnt(4)
    // (in-order retirement) = tile0's 4 landed.
    stage(Abase, 0,     0);   stage(Abase, 8192,  32);
    stage(Bbase, 16384, 0);   stage(Bbase, 24576, 32);
    stage(Abase, 32768 + 0,     64);  stage(Abase, 32768 + 8192,  96);
    stage(Bbase, 32768 + 16384, 64);  stage(Bbase, 32768 + 24576, 96);
    asm volatile("s_waitcnt vmcnt(4)" ::: "memory");
    __builtin_amdgcn_s_barrier();

    // stmode: 0 = steady (stage t+2), 1 = t62 (no stage, drain), 2 = t63
    auto ktile = [&](const int buf, const int t, const int stmode) {
        const int A0 = buf, A1 = buf + 8192;
        const int B0 = buf + 16384, B1 = buf + 24576;

        // k-half 0
        RD_B4(B0)
        RD_A2(A0, 0)  MM2(0)
        RD_A2(A0, 2)  MM2(2)
        __builtin_amdgcn_sched_barrier(0);   // cap liveness across halves
        // k-half 1
        RD_B4(B1)
        RD_A2(A1, 0)  MM2(0)
        RD_A2(A1, 2)  MM2(2)

        if (stmode == 2) return;             // straight to epilogue

        // all 16 reads of buf consumed by in-order MFMA issue above
        __builtin_amdgcn_s_barrier();

        if (stmode == 0) {                   // overwrite buf with tile t+2
            const int k2 = (t + 2) * 64;
            stage(Abase, A0, k2);  stage(Abase, A1, k2 + 32);
            stage(Bbase, B0, k2);  stage(Bbase, B1, k2 + 32);
            asm volatile("s_waitcnt vmcnt(4)" ::: "memory");  // t+1 landed
        } else {
            asm volatile("s_waitcnt vmcnt(0)" ::: "memory");  // drain t63
        }
        __builtin_amdgcn_s_barrier();        // t+1 globally visible
    };

    for (int t = 0; t < 62; t += 2) {
        ktile(0,     t,     0);
        ktile(32768, t + 1, 0);
    }
    ktile(0,     62, 1);
    ktile(32768, 63, 2);
#undef RD_B4
#undef RD_A2
#undef MM2

    // ---- epilogue: 16x16 C/D layout: col = lane&15, row = (lane>>4)*4 + reg
    const size_t row0 = bm + wmr + (gq << 2);
    const size_t col0 = bn + wnc + l16;
#pragma unroll
    for (int n = 0; n < 4; n++) {
        const size_t col = col0 + n * 16;
        const float bv = bias[col];
#pragma unroll
        for (int m = 0; m < 4; m++) {
            const size_t r = row0 + m * 16;
#pragma unroll
            for (int j = 0; j < 4; j++)
                C[(r + j) * N_DIM + col] = acc[m][n][j] + bv;
        }
    }
}

// ============================================================================
// Fallback (no workspace): previous-session 128x128 fp32-input kernel, verbatim.
// ============================================================================
#define BM 128
#define BN 128
#define BK 32

__global__ __launch_bounds__(256) void gemm_bt_f32(
    const float* __restrict__ Aptr, const float* __restrict__ Bptr,
    const float* __restrict__ bias, float* __restrict__ C) {

    __shared__ __align__(16) unsigned short As[BM * BK];
    __shared__ __align__(16) unsigned short Bs[BN * BK];

    const int tid  = threadIdx.x;
    const int wave = tid >> 6;
    const int lane = tid & 63;
    const int r32  = lane & 31;
    const int hi   = lane >> 5;

    const int bid = blockIdx.x;
    const int xcd = bid & 7;
    const int idx = bid >> 3;
    const int mt  = ((xcd & 1) << 4) + (idx & 15);
    const int nt  = (((xcd >> 1) & 3) << 3) + (idx >> 4);
    const int bm  = mt * BM;
    const int bn  = nt * BN;

    const int wm = (wave & 1) * 64;
    const int wn = (wave >> 1) * 64;

    f32x16 acc[2][2] = {};
    const int sw = (r32 >> 1) & 3;

    for (int k0 = 0; k0 < K_DIM; k0 += BK) {
        __syncthreads();
        {
            const int r  = tid >> 1;
            const int q0 = (tid & 1) << 1;
            const int s  = (r >> 1) & 3;
            {
                const float* sp = &Aptr[(size_t)(bm + r) * K_DIM + k0 + (q0 << 3)];
                float4 f0 = *(const float4*)(sp + 0);
                float4 f1 = *(const float4*)(sp + 4);
                float4 f2 = *(const float4*)(sp + 8);
                float4 f3 = *(const float4*)(sp + 12);
                u16x8 o0, o1;
                o0[0]=f2bf(f0.x); o0[1]=f2bf(f0.y); o0[2]=f2bf(f0.z); o0[3]=f2bf(f0.w);
                o0[4]=f2bf(f1.x); o0[5]=f2bf(f1.y); o0[6]=f2bf(f1.z); o0[7]=f2bf(f1.w);
                o1[0]=f2bf(f2.x); o1[1]=f2bf(f2.y); o1[2]=f2bf(f2.z); o1[3]=f2bf(f2.w);
                o1[4]=f2bf(f3.x); o1[5]=f2bf(f3.y); o1[6]=f2bf(f3.z); o1[7]=f2bf(f3.w);
                *(u16x8*)&As[r * BK + ((q0 ^ s) << 3)]       = o0;
                *(u16x8*)&As[r * BK + (((q0 + 1) ^ s) << 3)] = o1;
            }
            {
                const float* sp = &Bptr[(size_t)(bn + r) * K_DIM + k0 + (q0 << 3)];
                float4 f0 = *(const float4*)(sp + 0);
                float4 f1 = *(const float4*)(sp + 4);
                float4 f2 = *(const float4*)(sp + 8);
                float4 f3 = *(const float4*)(sp + 12);
                u16x8 o0, o1;
                o0[0]=f2bf(f0.x); o0[1]=f2bf(f0.y); o0[2]=f2bf(f0.z); o0[3]=f2bf(f0.w);
                o0[4]=f2bf(f1.x); o0[5]=f2bf(f1.y); o0[6]=f2bf(f1.z); o0[7]=f2bf(f1.w);
                o1[0]=f2bf(f2.x); o1[1]=f2bf(f2.y); o1[2]=f2bf(f2.z); o1[3]=f2bf(f2.w);
                o1[4]=f2bf(f3.x); o1[5]=f2bf(f3.y); o1[6]=f2bf(f3.z); o1[7]=f2bf(f3.w);
                *(u16x8*)&Bs[r * BK + ((q0 ^ s) << 3)]       = o0;
                *(u16x8*)&Bs[r * BK + (((q0 + 1) ^ s) << 3)] = o1;
            }
        }
        __syncthreads();

        bf16x8 af[2][2], bfv[2][2];
#pragma unroll
        for (int t = 0; t < 2; t++)
#pragma unroll
            for (int h = 0; h < 2; h++) {
                const int koffl = (((hi + 2 * h) ^ sw)) << 3;
                af[t][h]  = *(const bf16x8*)&As[(wm + t * 32 + r32) * BK + koffl];
                bfv[t][h] = *(const bf16x8*)&Bs[(wn + t * 32 + r32) * BK + koffl];
            }
#pragma unroll
        for (int h = 0; h < 2; h++)
#pragma unroll
            for (int i = 0; i < 2; i++)
#pragma unroll
                for (int j = 0; j < 2; j++)
                    acc[i][j] = __builtin_amdgcn_mfma_f32_32x32x16_bf16(
                        af[i][h], bfv[j][h], acc[i][j], 0, 0, 0);
    }

#pragma unroll
    for (int i = 0; i < 2; i++) {
        const int rowb = bm + wm + i * 32 + 4 * hi;
#pragma unroll
        for (int j = 0; j < 2; j++) {
            const int col = bn + wn + j * 32 + r32;
            const float bv = bias[col];
#pragma unroll
            for (int reg = 0; reg < 16; reg++) {
                const int row = rowb + (reg & 3) + 8 * (reg >> 2);
                C[(size_t)row * N_DIM + col] = acc[i][j][reg] + bv;
            }
        }
    }
}

extern "C" void kernel_launch(void* const* d_in, const int* in_sizes, int n_in,
                              void* d_out, int out_size, void* d_ws, size_t ws_size,
                              hipStream_t stream) {
    const float* x = (const float*)d_in[0];   // [M, K]
    const float* W = (const float*)d_in[1];   // [N, K]
    const float* b = (const float*)d_in[2];   // [N]
    float* out = (float*)d_out;               // [M, N]

    const size_t elems = (size_t)M_DIM * K_DIM;
    const size_t need  = 2 * elems * sizeof(unsigned short);  // 64 MB

    if (ws_size >= need) {
        unsigned short* xb = (unsigned short*)d_ws;
        unsigned short* wb = xb + elems;
        const int blocks_each = (int)(elems / (256 * 8));     // 8192
        cvt2_f32_to_bf16<<<2 * blocks_each, 256, 0, stream>>>(x, W, xb, wb, blocks_each);
        dim3 grid((M_DIM / 256) * (N_DIM / 256));             // 256 blocks = 1/CU
        gemm256<<<grid, dim3(1024), 0, stream>>>(xb, wb, b, out);
    } else {
        dim3 grid((M_DIM / BM) * (N_DIM / BN));
        gemm_bt_f32<<<grid, dim3(256), 0, stream>>>(x, W, b, out);
    }
}